// Round 1
// baseline (21082.921 us; speedup 1.0000x reference)
//
#include <hip/hip_runtime.h>
#include <math.h>

#define B 512
#define S_IN 128
#define S_OUT 64
#define T_DEC 63

// ---- workspace layout (in floats) ----
#define O_H0   0
#define O_C    (512*1024)
#define O_H1   (2*512*1024)
#define O_CUM  (3*512*1024)
#define O_HS0  (O_CUM + 512)
#define O_PWT  (O_HS0 + 128*512*512)
#define WS_FLOATS (O_PWT + 1024*128)

// ---------------------------------------------------------------------------
// Fused LSTM step: gates GEMM (gathered A, gate-interleaved B) + pointwise.
// MODE 0: encoder layer0 (K=64 emb + 256 h, N=1024, grid.z=dir)
// MODE 1: encoder layer1 (K=512 seq + 256 h, N=1024, grid.z=dir)
// MODE 2: decoder        (K=64 emb + 1024 h, N=4096)
// Output column n maps to gate g=n&3 of hidden unit jh=n>>2  (j = g*HH+jh),
// so each thread's 4x4 micro-tile holds i,f,g,o for 4 batch rows -> fused
// LSTM update in the epilogue. h double-buffered; c updated in place.
// ---------------------------------------------------------------------------
template<int MODE>
__global__ __launch_bounds__(256)
void step_kernel(const float* __restrict__ Wih, const float* __restrict__ Whh,
                 const float* __restrict__ bias,
                 const int* __restrict__ tok, const float* __restrict__ emb,
                 const float* __restrict__ seqin,
                 const float* __restrict__ h_in, float* __restrict__ h_out,
                 float* __restrict__ c_st, float* __restrict__ seqout, int t)
{
    constexpr int KE = (MODE==0) ? 64 : (MODE==1 ? 512 : 64);
    constexpr int KH = (MODE==2) ? 1024 : 256;
    constexpr int K  = KE + KH;
    constexpr int N  = (MODE==2) ? 4096 : 1024;
    constexpr int HH = N/4;
    constexpr int NK = K/16;

    const int dir   = (MODE==2) ? 0 : blockIdx.z;
    const int t_eff = (MODE==2) ? t : (dir ? (S_IN-1-t) : t);
    const int hseg  = (MODE==0) ? dir*256 : (MODE==1 ? 512 + dir*256 : 0);

    const float* Wih_d = Wih + (size_t)dir*N*KE;
    const float* Whh_d = Whh + (size_t)dir*N*KH;
    const float* b_d   = bias + dir*N;

    __shared__ float As[16][64];
    __shared__ float Bs[16][64];

    const int tid = threadIdx.x;
    const int bm0 = blockIdx.x*64;
    const int bn0 = blockIdx.y*64;

    // A tile load: 4 lanes per batch row, each a float4 of consecutive k
    const int la_m  = tid >> 2;
    const int la_k  = (tid & 3) << 2;
    const int a_row = bm0 + la_m;

    // B tile load: 4 lanes per output column, k-contiguous from original W
    const int lb_n = tid >> 2;
    const int lb_k = (tid & 3) << 2;
    const int n_g  = bn0 + lb_n;
    const int b_j  = (n_g & 3)*HH + (n_g >> 2);   // original weight row

    int tokidx = 0;
    if (MODE==0) tokidx = tok[t_eff*B + a_row];
    if (MODE==2) tokidx = tok[a_row*S_OUT + t];

    const int tm = (tid >> 4) << 2;   // 4 batch rows
    const int tn = (tid & 15) << 2;   // 4 cols = 4 gates of one jh

    float acc[4][4] = {};

    auto loadA = [&](int kt) -> float4 {
        int k = kt*16 + la_k;
        if (k < KE) {
            if (MODE==1) return *(const float4*)&seqin[((size_t)t_eff*B + a_row)*512 + k];
            else         return *(const float4*)&emb[(size_t)tokidx*64 + k];
        }
        return *(const float4*)&h_in[(size_t)a_row*1024 + hseg + (k-KE)];
    };
    auto loadB = [&](int kt) -> float4 {
        int k = kt*16 + lb_k;
        if (k < KE) return *(const float4*)&Wih_d[(size_t)b_j*KE + k];
        return *(const float4*)&Whh_d[(size_t)b_j*KH + (k-KE)];
    };

    float4 aR = loadA(0), bR = loadB(0);
    for (int kt=0; kt<NK; ++kt) {
        __syncthreads();
        As[la_k+0][la_m]=aR.x; As[la_k+1][la_m]=aR.y; As[la_k+2][la_m]=aR.z; As[la_k+3][la_m]=aR.w;
        Bs[lb_k+0][lb_n]=bR.x; Bs[lb_k+1][lb_n]=bR.y; Bs[lb_k+2][lb_n]=bR.z; Bs[lb_k+3][lb_n]=bR.w;
        __syncthreads();
        if (kt+1 < NK) { aR = loadA(kt+1); bR = loadB(kt+1); }
        #pragma unroll
        for (int k=0;k<16;k++){
            const float4 a = *(const float4*)&As[k][tm];
            const float4 b = *(const float4*)&Bs[k][tn];
            acc[0][0]+=a.x*b.x; acc[0][1]+=a.x*b.y; acc[0][2]+=a.x*b.z; acc[0][3]+=a.x*b.w;
            acc[1][0]+=a.y*b.x; acc[1][1]+=a.y*b.y; acc[1][2]+=a.y*b.z; acc[1][3]+=a.y*b.w;
            acc[2][0]+=a.z*b.x; acc[2][1]+=a.z*b.y; acc[2][2]+=a.z*b.z; acc[2][3]+=a.z*b.w;
            acc[3][0]+=a.w*b.x; acc[3][1]+=a.w*b.y; acc[3][2]+=a.w*b.z; acc[3][3]+=a.w*b.w;
        }
    }

    // ---- fused LSTM pointwise epilogue: cols are (i,f,g,o) of unit jh ----
    const int jh = (bn0 + tn) >> 2;
    const float bi = b_d[0*HH + jh];
    const float bf = b_d[1*HH + jh];
    const float bg = b_d[2*HH + jh];
    const float bo = b_d[3*HH + jh];
    #pragma unroll
    for (int i=0;i<4;i++){
        const int brow = bm0 + tm + i;
        float xi = acc[i][0] + bi;
        float xf = acc[i][1] + bf;
        float xg = acc[i][2] + bg;
        float xo = acc[i][3] + bo;
        float ig = 1.f/(1.f+expf(-xi));
        float fg = 1.f/(1.f+expf(-xf));
        float gg = tanhf(xg);
        float og = 1.f/(1.f+expf(-xo));
        size_t ci = (size_t)brow*1024 + hseg + jh;
        float cn = fg*c_st[ci] + ig*gg;
        float hn = og*tanhf(cn);
        c_st[ci]  = cn;
        h_out[ci] = hn;
        if (MODE==0) seqout[((size_t)t_eff*B + brow)*512 + dir*256 + jh] = hn;
    }
}

// ---------------------------------------------------------------------------
// Projection on CELL state + argmax + log_softmax gather. 4 batch rows/block.
// ---------------------------------------------------------------------------
__global__ __launch_bounds__(128)
void proj_kernel(const float* __restrict__ c, const float* __restrict__ wT,
                 const float* __restrict__ pb, const int* __restrict__ out_tok,
                 float* __restrict__ cum, float* __restrict__ dout, int t)
{
    __shared__ float cs[4][1024];
    __shared__ float ls[4][128];
    const int tid = threadIdx.x;
    const int b0 = blockIdx.x*4;
    #pragma unroll
    for (int r=0;r<4;r++){
        #pragma unroll
        for (int q=0;q<2;q++){
            int k = (q*128 + tid)*4;
            *(float4*)&cs[r][k] = *(const float4*)&c[((size_t)(b0+r))*1024 + k];
        }
    }
    __syncthreads();
    float a0=0.f,a1=0.f,a2=0.f,a3=0.f;
    for (int k=0;k<1024;k++){
        float w = wT[k*128 + tid];
        a0 += w*cs[0][k]; a1 += w*cs[1][k]; a2 += w*cs[2][k]; a3 += w*cs[3][k];
    }
    float bb = pb[tid];
    ls[0][tid]=a0+bb; ls[1][tid]=a1+bb; ls[2][tid]=a2+bb; ls[3][tid]=a3+bb;
    __syncthreads();
    if (tid < 4){
        const int r = tid, b = b0 + r;
        float m = ls[r][0]; int am = 0;
        for (int j=1;j<128;j++){ float v=ls[r][j]; if (v>m){m=v;am=j;} }  // first-max
        float s=0.f;
        for (int j=0;j<128;j++) s += expf(ls[r][j]-m);
        int tnx = out_tok[b*S_OUT + t + 1];
        float logp = ls[r][tnx] - m - logf(s);
        float cn = ((t==0)?0.f:cum[b]) + logp;
        cum[b] = cn;
        dout[T_DEC*B + b] = cn;          // final write (t=62) is the answer
        dout[t*B + b] = (float)am;
    }
}

__global__ void transpose_proj(const float* __restrict__ W, float* __restrict__ WT){
    int idx = blockIdx.x*blockDim.x + threadIdx.x;
    if (idx < 1024*128){
        int j = idx & 127, k = idx >> 7;
        WT[idx] = W[j*1024 + k];
    }
}

__global__ void zero_kernel(float* __restrict__ p, int n){
    int i = blockIdx.x*blockDim.x + threadIdx.x;
    if (i < n) p[i] = 0.f;
}

extern "C" void kernel_launch(void* const* d_in, const int* in_sizes, int n_in,
                              void* d_out, int out_size, void* d_ws, size_t ws_size,
                              hipStream_t stream)
{
    const int*   input_tokens  = (const int*)d_in[0];
    const int*   output_tokens = (const int*)d_in[1];
    const float* in_emb  = (const float*)d_in[2];
    const float* eWih0   = (const float*)d_in[3];
    const float* eWhh0   = (const float*)d_in[4];
    const float* eb0     = (const float*)d_in[5];
    const float* eWih1   = (const float*)d_in[6];
    const float* eWhh1   = (const float*)d_in[7];
    const float* eb1     = (const float*)d_in[8];
    const float* out_emb = (const float*)d_in[9];
    const float* dWih    = (const float*)d_in[10];
    const float* dWhh    = (const float*)d_in[11];
    const float* db      = (const float*)d_in[12];
    const float* pW      = (const float*)d_in[13];
    const float* pb      = (const float*)d_in[14];

    if (ws_size < (size_t)WS_FLOATS * 4) return;  // workspace too small: bail

    float* ws  = (float*)d_ws;
    float* out = (float*)d_out;

    float* h[2] = { ws + O_H0, ws + O_H1 };
    float* c    = ws + O_C;
    float* cum  = ws + O_CUM;
    float* hs0  = ws + O_HS0;
    float* pwt  = ws + O_PWT;

    // init: zero h buffer 0 and c (contiguous: [O_H0, O_C+512*1024))
    zero_kernel<<<4096,256,0,stream>>>(ws, 2*512*1024);
    transpose_proj<<<512,256,0,stream>>>(pW, pwt);

    // encoder layer 0 (both directions per launch; h state segs [0,512))
    for (int t=0;t<S_IN;t++)
        step_kernel<0><<<dim3(8,16,2),256,0,stream>>>(eWih0, eWhh0, eb0,
            input_tokens, in_emb, nullptr, h[t&1], h[(t+1)&1], c, hs0, t);

    // encoder layer 1 (reads hs0; h state segs [512,1024)); seq output dead
    for (int t=0;t<S_IN;t++)
        step_kernel<1><<<dim3(8,16,2),256,0,stream>>>(eWih1, eWhh1, eb1,
            nullptr, nullptr, hs0, h[t&1], h[(t+1)&1], c, nullptr, t);

    // decoder: h[0]/c now hold (l0f,l0b,l1f,l1b) finals = (h0,c0) exactly
    for (int t=0;t<T_DEC;t++){
        step_kernel<2><<<dim3(8,64,1),256,0,stream>>>(dWih, dWhh, db,
            output_tokens, out_emb, nullptr, h[t&1], h[(t+1)&1], c, nullptr, t);
        proj_kernel<<<128,128,0,stream>>>(c, pwt, pb, output_tokens, cum, out, t);
    }
}

// Round 2
// 16890.576 us; speedup vs baseline: 1.2482x; 1.2482x over previous
//
#include <hip/hip_runtime.h>
#include <math.h>

#define B 512
#define S_IN 128
#define S_OUT 64
#define T_DEC 63

// ---- workspace layout (floats) ----
#define O_H0   0
#define O_H1   (512*1024)
#define O_C    (2*512*1024)
#define O_CUM  (3*512*1024)
#define O_HS0  (O_CUM + 512)            // 1,573,376
#define O_P1   (O_HS0 + 128*512*512)    // 35,127,808 floats = 140.5 MB base

// ===========================================================================
// Encoder step (256 thr, 64x64 tile, 4x4 micro).
// MODE 0: layer0, K=64(emb)+256(h), writes hs0
// MODE 1: layer1 fast, K=256(h), adds precomputed P1 in epilogue
// MODE 2: layer1 legacy, K=512(hs0)+256(h)  (fallback if ws too small)
// Gate-interleaved B gather: col n -> weight row j=(n&3)*256+(n>>2), so each
// thread's 4 cols are i,f,g,o of one hidden unit -> fused LSTM epilogue.
// ===========================================================================
template<int MODE>
__global__ __launch_bounds__(256)
void enc_step(const float* __restrict__ Wih, const float* __restrict__ Whh,
              const float* __restrict__ bias, const int* __restrict__ tok,
              const float* __restrict__ emb, const float* __restrict__ seqin,
              const float* __restrict__ h_in, float* __restrict__ h_out,
              float* __restrict__ c_st, float* __restrict__ seqout,
              const float* __restrict__ p1, int t)
{
    constexpr int KE = (MODE==0) ? 64 : (MODE==2 ? 512 : 0);
    constexpr int K  = KE + 256;
    constexpr int NK = K/16;

    const int dir   = blockIdx.z;
    const int t_eff = dir ? (S_IN-1-t) : t;
    const int hseg  = (MODE==0) ? dir*256 : 512 + dir*256;

    const float* Wih_d = Wih + (size_t)dir*1024*KE;
    const float* Whh_d = Whh + (size_t)dir*1024*256;
    const float* b_d   = bias + dir*1024;

    __shared__ float As[16][64];
    __shared__ float Bs[16][64];

    const int tid = threadIdx.x;
    const int bm0 = blockIdx.x*64;
    const int bn0 = blockIdx.y*64;

    const int la_m  = tid >> 2;
    const int la_k  = (tid & 3) << 2;
    const int a_row = bm0 + la_m;

    const int lb_n = tid >> 2;
    const int lb_k = (tid & 3) << 2;
    const int n_g  = bn0 + lb_n;
    const int b_j  = (n_g & 3)*256 + (n_g >> 2);

    int tokidx = 0;
    if (MODE==0) tokidx = tok[t_eff*B + a_row];

    const int tm = (tid >> 4) << 2;
    const int tn = (tid & 15) << 2;

    float acc[4][4] = {};

    auto loadA = [&](int kt) -> float4 {
        int k = kt*16 + la_k;
        if (MODE==0) {
            if (k < 64) return *(const float4*)&emb[(size_t)tokidx*64 + k];
            return *(const float4*)&h_in[(size_t)a_row*1024 + hseg + (k-64)];
        } else if (MODE==2) {
            if (k < 512) return *(const float4*)&seqin[((size_t)t_eff*B + a_row)*512 + k];
            return *(const float4*)&h_in[(size_t)a_row*1024 + hseg + (k-512)];
        } else {
            return *(const float4*)&h_in[(size_t)a_row*1024 + hseg + k];
        }
    };
    auto loadB = [&](int kt) -> float4 {
        int k = kt*16 + lb_k;
        if (KE && k < KE) return *(const float4*)&Wih_d[(size_t)b_j*KE + k];
        return *(const float4*)&Whh_d[(size_t)b_j*256 + (k-KE)];
    };

    float4 aR = loadA(0), bR = loadB(0);
    for (int kt=0; kt<NK; ++kt) {
        __syncthreads();
        As[la_k+0][la_m]=aR.x; As[la_k+1][la_m]=aR.y; As[la_k+2][la_m]=aR.z; As[la_k+3][la_m]=aR.w;
        Bs[lb_k+0][lb_n]=bR.x; Bs[lb_k+1][lb_n]=bR.y; Bs[lb_k+2][lb_n]=bR.z; Bs[lb_k+3][lb_n]=bR.w;
        __syncthreads();
        if (kt+1 < NK) { aR = loadA(kt+1); bR = loadB(kt+1); }
        #pragma unroll
        for (int k=0;k<16;k++){
            const float4 a = *(const float4*)&As[k][tm];
            const float4 b = *(const float4*)&Bs[k][tn];
            acc[0][0]+=a.x*b.x; acc[0][1]+=a.x*b.y; acc[0][2]+=a.x*b.z; acc[0][3]+=a.x*b.w;
            acc[1][0]+=a.y*b.x; acc[1][1]+=a.y*b.y; acc[1][2]+=a.y*b.z; acc[1][3]+=a.y*b.w;
            acc[2][0]+=a.z*b.x; acc[2][1]+=a.z*b.y; acc[2][2]+=a.z*b.z; acc[2][3]+=a.z*b.w;
            acc[3][0]+=a.w*b.x; acc[3][1]+=a.w*b.y; acc[3][2]+=a.w*b.z; acc[3][3]+=a.w*b.w;
        }
    }

    const int jh = (bn0 + tn) >> 2;
    const float bi = b_d[0*256 + jh];
    const float bf = b_d[1*256 + jh];
    const float bg = b_d[2*256 + jh];
    const float bo = b_d[3*256 + jh];
    #pragma unroll
    for (int i=0;i<4;i++){
        const int brow = bm0 + tm + i;
        float xi = acc[i][0] + bi;
        float xf = acc[i][1] + bf;
        float xg = acc[i][2] + bg;
        float xo = acc[i][3] + bo;
        if (MODE==1) {
            const float4 pv = *(const float4*)&p1[((size_t)dir*512 + brow)*1024 + bn0 + tn];
            xi += pv.x; xf += pv.y; xg += pv.z; xo += pv.w;
        }
        float ig = 1.f/(1.f+expf(-xi));
        float fg = 1.f/(1.f+expf(-xf));
        float gg = tanhf(xg);
        float og = 1.f/(1.f+expf(-xo));
        size_t ci = (size_t)brow*1024 + hseg + jh;
        float cn = fg*c_st[ci] + ig*gg;
        float hn = og*tanhf(cn);
        c_st[ci]  = cn;
        h_out[ci] = hn;
        if (MODE==0) seqout[((size_t)t_eff*B + brow)*512 + dir*256 + jh] = hn;
    }
}

// ===========================================================================
// 128-thread GEMM, 64x64 tile, 4x8 micro (1.33 FLOP/LDS-byte).
// MODE 0: decoder step (K=64 emb + 1024 h, N=4096, fused LSTM epilogue)
// MODE 1: P1 precompute (A=hs0 rows gathered by (s,dir), K=512, N=1024, store)
// ===========================================================================
template<int MODE>
__global__ __launch_bounds__(128)
void gemm128(const float* __restrict__ Wih, const float* __restrict__ Whh,
             const float* __restrict__ bias, const int* __restrict__ tok,
             const float* __restrict__ emb, const float* __restrict__ hs0,
             const float* __restrict__ h_in, float* __restrict__ h_out,
             float* __restrict__ c_st, float* __restrict__ p1out, int t_or_s0)
{
    constexpr int KE = (MODE==0) ? 64 : 0;
    constexpr int K  = (MODE==0) ? 1088 : 512;
    constexpr int NK = K/16;
    constexpr int HH = (MODE==0) ? 1024 : 256;

    const int dir = (MODE==1) ? blockIdx.z : 0;

    __shared__ float As[16][64];
    __shared__ float Bs[16][64];

    const int tid = threadIdx.x;
    const int bm0 = blockIdx.x*64;
    const int bn0 = blockIdx.y*64;

    // loaders: 2 float4 per thread per operand
    const int la_m  = tid >> 1;
    const int la_k  = (tid & 1) << 3;
    const int a_row = bm0 + la_m;

    const int srel  = (MODE==1) ? (blockIdx.x >> 3) : 0;     // s within chunk
    const int sabs  = (MODE==1) ? (t_or_s0 + srel) : 0;
    const int t_eff = (MODE==1) ? (dir ? (S_IN-1-sabs) : sabs) : 0;
    const int a_b   = a_row & 511;

    const int n_g = bn0 + la_m;          // B row uses same tid>>1 pattern
    const int b_j = (n_g & 3)*HH + (n_g >> 2);

    const float* Wih_d = (MODE==1) ? (Wih + (size_t)dir*1024*512) : Wih;

    int tokidx = 0;
    if (MODE==0) tokidx = tok[a_row*S_OUT + t_or_s0];

    const int tm = (tid >> 3) << 2;      // 4 rows
    const int tn = (tid & 7) << 3;       // 8 cols = 2 hidden units

    float acc[4][8] = {};

    auto loadA = [&](int kt, int q) -> float4 {
        int k = kt*16 + la_k + q*4;
        if (MODE==0) {
            if (k < 64) return *(const float4*)&emb[(size_t)tokidx*64 + k];
            return *(const float4*)&h_in[(size_t)a_row*1024 + (k-64)];
        }
        return *(const float4*)&hs0[((size_t)t_eff*B + a_b)*512 + k];
    };
    auto loadB = [&](int kt, int q) -> float4 {
        int k = kt*16 + la_k + q*4;
        if (MODE==0) {
            if (k < 64) return *(const float4*)&Wih[(size_t)b_j*64 + k];
            return *(const float4*)&Whh[(size_t)b_j*1024 + (k-64)];
        }
        return *(const float4*)&Wih_d[(size_t)b_j*512 + k];
    };

    float4 aR0 = loadA(0,0), aR1 = loadA(0,1);
    float4 bR0 = loadB(0,0), bR1 = loadB(0,1);
    for (int kt=0; kt<NK; ++kt) {
        __syncthreads();
        As[la_k+0][la_m]=aR0.x; As[la_k+1][la_m]=aR0.y; As[la_k+2][la_m]=aR0.z; As[la_k+3][la_m]=aR0.w;
        As[la_k+4][la_m]=aR1.x; As[la_k+5][la_m]=aR1.y; As[la_k+6][la_m]=aR1.z; As[la_k+7][la_m]=aR1.w;
        Bs[la_k+0][la_m]=bR0.x; Bs[la_k+1][la_m]=bR0.y; Bs[la_k+2][la_m]=bR0.z; Bs[la_k+3][la_m]=bR0.w;
        Bs[la_k+4][la_m]=bR1.x; Bs[la_k+5][la_m]=bR1.y; Bs[la_k+6][la_m]=bR1.z; Bs[la_k+7][la_m]=bR1.w;
        __syncthreads();
        if (kt+1 < NK) {
            aR0 = loadA(kt+1,0); aR1 = loadA(kt+1,1);
            bR0 = loadB(kt+1,0); bR1 = loadB(kt+1,1);
        }
        #pragma unroll
        for (int k=0;k<16;k++){
            const float4 a  = *(const float4*)&As[k][tm];
            const float4 b0 = *(const float4*)&Bs[k][tn];
            const float4 b1 = *(const float4*)&Bs[k][tn+4];
            acc[0][0]+=a.x*b0.x; acc[0][1]+=a.x*b0.y; acc[0][2]+=a.x*b0.z; acc[0][3]+=a.x*b0.w;
            acc[0][4]+=a.x*b1.x; acc[0][5]+=a.x*b1.y; acc[0][6]+=a.x*b1.z; acc[0][7]+=a.x*b1.w;
            acc[1][0]+=a.y*b0.x; acc[1][1]+=a.y*b0.y; acc[1][2]+=a.y*b0.z; acc[1][3]+=a.y*b0.w;
            acc[1][4]+=a.y*b1.x; acc[1][5]+=a.y*b1.y; acc[1][6]+=a.y*b1.z; acc[1][7]+=a.y*b1.w;
            acc[2][0]+=a.z*b0.x; acc[2][1]+=a.z*b0.y; acc[2][2]+=a.z*b0.z; acc[2][3]+=a.z*b0.w;
            acc[2][4]+=a.z*b1.x; acc[2][5]+=a.z*b1.y; acc[2][6]+=a.z*b1.z; acc[2][7]+=a.z*b1.w;
            acc[3][0]+=a.w*b0.x; acc[3][1]+=a.w*b0.y; acc[3][2]+=a.w*b0.z; acc[3][3]+=a.w*b0.w;
            acc[3][4]+=a.w*b1.x; acc[3][5]+=a.w*b1.y; acc[3][6]+=a.w*b1.z; acc[3][7]+=a.w*b1.w;
        }
    }

    if (MODE==0) {
        const int jh0 = (bn0 + tn) >> 2;
        #pragma unroll
        for (int u=0;u<2;u++){
            const int jh = jh0 + u;
            const float bi = bias[0*1024 + jh];
            const float bf = bias[1*1024 + jh];
            const float bg = bias[2*1024 + jh];
            const float bo = bias[3*1024 + jh];
            #pragma unroll
            for (int i=0;i<4;i++){
                const int brow = bm0 + tm + i;
                float xi = acc[i][4*u+0] + bi;
                float xf = acc[i][4*u+1] + bf;
                float xg = acc[i][4*u+2] + bg;
                float xo = acc[i][4*u+3] + bo;
                float ig = 1.f/(1.f+expf(-xi));
                float fg = 1.f/(1.f+expf(-xf));
                float gg = tanhf(xg);
                float og = 1.f/(1.f+expf(-xo));
                size_t ci = (size_t)brow*1024 + jh;
                float cn = fg*c_st[ci] + ig*gg;
                float hn = og*tanhf(cn);
                c_st[ci]  = cn;
                h_out[ci] = hn;
            }
        }
    } else {
        #pragma unroll
        for (int i=0;i<4;i++){
            const int r = bm0 + tm + i;
            size_t base = ((size_t)(srel*2 + dir)*512 + (r & 511))*1024 + bn0 + tn;
            *(float4*)&p1out[base]   = *(float4*)&acc[i][0];
            *(float4*)&p1out[base+4] = *(float4*)&acc[i][4];
        }
    }
}

// ===========================================================================
// Projection on cell state + argmax(first) + log_softmax gather.
// 64 blocks x 256 thr, 8 batch rows per block; wave-parallel reductions.
// ===========================================================================
__global__ __launch_bounds__(256)
void proj2(const float* __restrict__ c, const float* __restrict__ pW,
           const float* __restrict__ pb, const int* __restrict__ out_tok,
           float* __restrict__ cum, float* __restrict__ dout, int t)
{
    __shared__ float cs[8][1024];
    __shared__ float ls[8][128];
    const int tid = threadIdx.x;
    const int b0 = blockIdx.x*8;
    #pragma unroll
    for (int r=0;r<8;r++)
        *(float4*)&cs[r][tid*4] = *(const float4*)&c[(size_t)(b0+r)*1024 + tid*4];
    __syncthreads();

    const int wave = tid >> 6, lane = tid & 63;
    const int col  = wave*32 + (lane & 31);      // 4 waves x 32 cols = 128
    const int rb   = (lane >> 5) * 4;            // half-wave: rows 0-3 / 4-7
    float a0=0.f,a1=0.f,a2=0.f,a3=0.f;
    for (int k=0;k<1024;k+=4){
        const float4 w = *(const float4*)&pW[(size_t)col*1024 + k];
        const float4 c0 = *(const float4*)&cs[rb+0][k];
        const float4 c1 = *(const float4*)&cs[rb+1][k];
        const float4 c2 = *(const float4*)&cs[rb+2][k];
        const float4 c3 = *(const float4*)&cs[rb+3][k];
        a0 += w.x*c0.x + w.y*c0.y + w.z*c0.z + w.w*c0.w;
        a1 += w.x*c1.x + w.y*c1.y + w.z*c1.z + w.w*c1.w;
        a2 += w.x*c2.x + w.y*c2.y + w.z*c2.z + w.w*c2.w;
        a3 += w.x*c3.x + w.y*c3.y + w.z*c3.z + w.w*c3.w;
    }
    const float bb = pb[col];
    ls[rb+0][col]=a0+bb; ls[rb+1][col]=a1+bb; ls[rb+2][col]=a2+bb; ls[rb+3][col]=a3+bb;
    __syncthreads();

    // each wave finalizes 2 rows
    #pragma unroll
    for (int rr=0;rr<2;rr++){
        const int r = wave*2 + rr, b = b0 + r;
        float v0 = ls[r][lane], v1 = ls[r][lane+64];
        // argmax with first-occurrence tie-break
        float mv; int mi;
        if (v1 > v0) { mv = v1; mi = lane+64; } else { mv = v0; mi = lane; }
        #pragma unroll
        for (int o=32;o>=1;o>>=1){
            float ov = __shfl_xor(mv, o);
            int   oi = __shfl_xor(mi, o);
            if (ov > mv || (ov == mv && oi < mi)) { mv = ov; mi = oi; }
        }
        float e = expf(v0 - mv) + expf(v1 - mv);
        #pragma unroll
        for (int o=32;o>=1;o>>=1) e += __shfl_xor(e, o);
        if (lane == 0){
            const int tnx = out_tok[b*S_OUT + t + 1];
            const float lv = ls[r][tnx];
            const float logp = lv - mv - logf(e);
            const float cn = ((t==0) ? 0.f : cum[b]) + logp;
            cum[b] = cn;
            dout[T_DEC*B + b] = cn;
            dout[t*B + b] = (float)mi;
        }
    }
}

__global__ void zero_kernel(float* __restrict__ p, int n4){
    int i = blockIdx.x*blockDim.x + threadIdx.x;
    if (i < n4) *(float4*)&p[i*4] = float4{0.f,0.f,0.f,0.f};
}

extern "C" void kernel_launch(void* const* d_in, const int* in_sizes, int n_in,
                              void* d_out, int out_size, void* d_ws, size_t ws_size,
                              hipStream_t stream)
{
    const int*   input_tokens  = (const int*)d_in[0];
    const int*   output_tokens = (const int*)d_in[1];
    const float* in_emb  = (const float*)d_in[2];
    const float* eWih0   = (const float*)d_in[3];
    const float* eWhh0   = (const float*)d_in[4];
    const float* eb0     = (const float*)d_in[5];
    const float* eWih1   = (const float*)d_in[6];
    const float* eWhh1   = (const float*)d_in[7];
    const float* eb1     = (const float*)d_in[8];
    const float* out_emb = (const float*)d_in[9];
    const float* dWih    = (const float*)d_in[10];
    const float* dWhh    = (const float*)d_in[11];
    const float* db      = (const float*)d_in[12];
    const float* pW      = (const float*)d_in[13];
    const float* pb      = (const float*)d_in[14];

    size_t ws_fl = ws_size / 4;
    if (ws_fl < (size_t)O_P1) return;

    int CH = 0;
    if      (ws_fl >= (size_t)O_P1 + 16u*1048576u) CH = 16;
    else if (ws_fl >= (size_t)O_P1 +  8u*1048576u) CH = 8;
    else if (ws_fl >= (size_t)O_P1 +  4u*1048576u) CH = 4;
    else if (ws_fl >= (size_t)O_P1 +  2u*1048576u) CH = 2;

    float* ws  = (float*)d_ws;
    float* out = (float*)d_out;

    float* h[2] = { ws + O_H0, ws + O_H1 };
    float* c    = ws + O_C;
    float* cum  = ws + O_CUM;
    float* hs0  = ws + O_HS0;
    float* p1   = ws + O_P1;

    // zero h0,h1,c,cum
    zero_kernel<<<(O_HS0/4 + 255)/256, 256, 0, stream>>>(ws, O_HS0/4);

    // ---- encoder layer 0 ----
    for (int t=0;t<S_IN;t++)
        enc_step<0><<<dim3(8,16,2),256,0,stream>>>(eWih0, eWhh0, eb0,
            input_tokens, in_emb, nullptr, h[t&1], h[(t+1)&1], c, hs0, nullptr, t);

    // ---- encoder layer 1 ----
    if (CH) {
        for (int s0=0; s0<S_IN; s0+=CH) {
            gemm128<1><<<dim3(CH*8,16,2),128,0,stream>>>(eWih1, nullptr, nullptr,
                nullptr, nullptr, hs0, nullptr, nullptr, nullptr, p1, s0);
            for (int s=s0; s<s0+CH; ++s)
                enc_step<1><<<dim3(8,16,2),256,0,stream>>>(eWih1, eWhh1, eb1,
                    nullptr, nullptr, nullptr, h[s&1], h[(s+1)&1], c, nullptr,
                    p1 + (size_t)(s-s0)*2*512*1024, s);
        }
    } else {
        for (int t=0;t<S_IN;t++)
            enc_step<2><<<dim3(8,16,2),256,0,stream>>>(eWih1, eWhh1, eb1,
                nullptr, nullptr, hs0, h[t&1], h[(t+1)&1], c, nullptr, nullptr, t);
    }

    // ---- decoder ----
    for (int t=0;t<T_DEC;t++){
        gemm128<0><<<dim3(8,64,1),128,0,stream>>>(dWih, dWhh, db,
            output_tokens, out_emb, nullptr, h[t&1], h[(t+1)&1], c, nullptr, t);
        proj2<<<64,256,0,stream>>>(c, pW, pb, output_tokens, cum, out, t);
    }
}